// Round 1
// baseline (296.542 us; speedup 1.0000x reference)
//
#include <hip/hip_runtime.h>

#define NTOK  131072
#define DDIM  192
#define KMEM  128
#define TWOD  384
#define SIMBLK 2048  // sim grid: 64 tokens per block
#define CVBLK  1024  // cv / argmax grids: 128 tokens per block

typedef _Float16 half8 __attribute__((ext_vector_type(8)));
typedef float   floatx4 __attribute__((ext_vector_type(4)));

// ---------------------------------------------------------------------------
// prep: L2-normalize mem_bank rows -> fp16x2 split (hi, lo*4096) global arrays;
// precompute GLU(mem_bank) table (K distinct rows only).
// ---------------------------------------------------------------------------
__global__ __launch_bounds__(192) void prep_kernel(
    const float* __restrict__ mb, const float* __restrict__ W,
    const float* __restrict__ bias, _Float16* __restrict__ bhi,
    _Float16* __restrict__ blo, float* __restrict__ tab) {
  __shared__ float row[DDIM];
  __shared__ float red[DDIM];
  __shared__ float s_rn;
  const int k = blockIdx.x;
  const int t = threadIdx.x;  // 0..191
  float m = mb[k * DDIM + t];
  row[t] = m;
  red[t] = m * m;
  __syncthreads();
  if (t == 0) {
    float s = 0.f;
    for (int i = 0; i < DDIM; ++i) s += red[i];
    s_rn = 1.0f / sqrtf(fmaxf(s, 1e-12f));
  }
  __syncthreads();
  const float mn = m * s_rn;
  const _Float16 hh = (_Float16)mn;
  const float lo = (mn - (float)hh) * 4096.0f;
  bhi[k * DDIM + t] = hh;
  blo[k * DDIM + t] = (_Float16)lo;
  float a = bias[t], g = bias[DDIM + t];
  for (int d = 0; d < DDIM; ++d) {
    float r = row[d];
    a = fmaf(r, W[d * TWOD + t], a);
    g = fmaf(r, W[d * TWOD + DDIM + t], g);
  }
  float sg = 1.0f / (1.0f + expf(-g));
  tab[k * DDIM + t] = a * sg;
}

// ---------------------------------------------------------------------------
// sim v2: 64 tokens/block, K-inner loop over fully-staged A tile.
//  - A (proj) hi/lo staged once to LDS (51 KB), ONE __syncthreads per block.
//  - B fragments loaded directly from global (96 KB total, L2-resident),
//    cached in registers per 16-code strip.
//  - Per-16x16-tile accumulators (8 VGPRs live) + immediate epilogue:
//    norm -> exp -> store E -> rowsum accumulate.
//  - Each wave owns disjoint 32 codes -> register-only rowsum reduction.
// ---------------------------------------------------------------------------
#define LSTR 200  // halfs per LDS row: 400 B = 25*16 B (odd multiple of 16)
__global__ __launch_bounds__(256, 3) void sim_kernel(
    const float* __restrict__ proj, const _Float16* __restrict__ bhi_g,
    const _Float16* __restrict__ blo_g, float* __restrict__ E,
    double* __restrict__ RpT) {
  __shared__ _Float16 Ahi[64 * LSTR];
  __shared__ _Float16 Alo[64 * LSTR];
  __shared__ float rn_s[64];
  const int tid = threadIdx.x;
  const int lane = tid & 63;
  const int wid = tid >> 6;  // wave owns codes [wid*32, wid*32+32)
  const long n0 = (long)blockIdx.x * 64;

  // ---- stage A: 4 threads per token row, 48 contiguous floats each ----
  {
    const int row = tid >> 2;   // 0..63
    const int part = tid & 3;   // 0..3
    const float* src = &proj[(n0 + row) * DDIM + part * 48];
    const int lb0 = row * LSTR + part * 48;
    float nsq = 0.f;
#pragma unroll
    for (int i = 0; i < 6; ++i) {
      float4 p0 = *(const float4*)(src + i * 8);
      float4 p1 = *(const float4*)(src + i * 8 + 4);
      float xs[8] = {p0.x, p0.y, p0.z, p0.w, p1.x, p1.y, p1.z, p1.w};
      half8 h, l;
#pragma unroll
      for (int j = 0; j < 8; ++j) {
        float x = xs[j];
        nsq = fmaf(x, x, nsq);
        _Float16 hh = (_Float16)x;
        h[j] = hh;
        l[j] = (_Float16)((x - (float)hh) * 4096.0f);
      }
      *(half8*)&Ahi[lb0 + i * 8] = h;
      *(half8*)&Alo[lb0 + i * 8] = l;
    }
    nsq += __shfl_xor(nsq, 1);
    nsq += __shfl_xor(nsq, 2);
    if (part == 0) rn_s[row] = 1.0f / sqrtf(fmaxf(nsq, 1e-12f));
  }
  __syncthreads();

  const int m_row = lane & 15;
  const int quad = lane >> 4;
  const int code_base = wid * 32;

  // token norms this lane needs (same 16 tokens for every tile row)
  float rnv[16];
#pragma unroll
  for (int sm = 0; sm < 4; ++sm)
#pragma unroll
    for (int r = 0; r < 4; ++r) rnv[sm * 4 + r] = rn_s[sm * 16 + quad * 4 + r];

  float rcol[2] = {0.f, 0.f};
#pragma unroll
  for (int sn = 0; sn < 2; ++sn) {
    const int code = code_base + sn * 16 + m_row;
    // preload this code strip's B fragments for all 6 k-chunks (registers)
    half8 bh[6], bl[6];
#pragma unroll
    for (int c = 0; c < 6; ++c) {
      const int gb = code * DDIM + c * 32 + quad * 8;
      bh[c] = *(const half8*)&bhi_g[gb];
      bl[c] = *(const half8*)&blo_g[gb];
    }
#pragma unroll
    for (int sm = 0; sm < 4; ++sm) {
      floatx4 a1 = (floatx4)0.0f;
      floatx4 a2 = (floatx4)0.0f;
#pragma unroll
      for (int c = 0; c < 6; ++c) {
        const int ar = (sm * 16 + m_row) * LSTR + c * 32 + quad * 8;
        half8 ah = *(const half8*)&Ahi[ar];
        half8 al = *(const half8*)&Alo[ar];
        a1 = __builtin_amdgcn_mfma_f32_16x16x32_f16(ah, bh[c], a1, 0, 0, 0);
        a2 = __builtin_amdgcn_mfma_f32_16x16x32_f16(ah, bl[c], a2, 0, 0, 0);
        a2 = __builtin_amdgcn_mfma_f32_16x16x32_f16(al, bh[c], a2, 0, 0, 0);
      }
      // immediate per-tile epilogue (same combine/exp numerics as before)
#pragma unroll
      for (int r = 0; r < 4; ++r) {
        const int tok = sm * 16 + quad * 4 + r;
        const float sim = fmaf(a2[r], 0.000244140625f, a1[r]) * rnv[sm * 4 + r];
        const float e = expf(sim / 0.05f);
        E[(n0 + tok) * KMEM + code] = e;
        rcol[sn] += e;
      }
    }
  }
  // reduce over the 4 quads sharing each code column; lanes 0..15 hold sums
#pragma unroll
  for (int sn = 0; sn < 2; ++sn) {
    rcol[sn] += __shfl_xor(rcol[sn], 16);
    rcol[sn] += __shfl_xor(rcol[sn], 32);
  }
  if (lane < 16) {
    RpT[(long)(code_base + lane) * SIMBLK + blockIdx.x] = (double)rcol[0];
    RpT[(long)(code_base + 16 + lane) * SIMBLK + blockIdx.x] = (double)rcol[1];
  }
}

// ---------------------------------------------------------------------------
// u update: u[k] = 1/(K * sum_b RpT[k][b]). One block per k, coalesced,
// deterministic fixed-order fp64. width = number of partials per k.
// ---------------------------------------------------------------------------
__global__ __launch_bounds__(256) void u_kernel(const double* __restrict__ RpT,
                                                float* __restrict__ u,
                                                int width) {
  __shared__ double wred[4];
  const int k = blockIdx.x;
  const int t = threadIdx.x;
  double s = 0.0;
  for (int j = t; j < width; j += 256) s += RpT[(long)k * width + j];
#pragma unroll
  for (int off = 1; off < 64; off <<= 1) s += __shfl_xor(s, off);
  if ((t & 63) == 0) wred[t >> 6] = s;
  __syncthreads();
  if (t == 0)
    u[k] = (float)(1.0 / (128.0 * (wred[0] + wred[1] + wred[2] + wred[3])));
}

// ---------------------------------------------------------------------------
// cv: per token colsum C = dot(E_row, u); v = 1/(N*C); RpT[k][blk] += E*v.
// 8 lanes per token (16 k's each), 3-level shfl, 128 tokens per block.
// ---------------------------------------------------------------------------
__global__ __launch_bounds__(256) void cv_kernel(const float* __restrict__ E,
                                                 const float* __restrict__ u,
                                                 double* __restrict__ RpT) {
  __shared__ double part[4][KMEM];
  const int tid = threadIdx.x;
  const int l = tid & 7;    // lane-in-token
  const int ts = tid >> 3;  // token slot 0..31
  const long n0 = (long)blockIdx.x * 128;
  float4 u4[4];
#pragma unroll
  for (int j = 0; j < 4; ++j) u4[j] = *(const float4*)&u[l * 16 + j * 4];
  double r[16];
#pragma unroll
  for (int i = 0; i < 16; ++i) r[i] = 0.0;
#pragma unroll
  for (int it = 0; it < 4; ++it) {
    const long n = n0 + it * 32 + ts;
    const float* Er = &E[n * KMEM + l * 16];
    const float4 e0 = *(const float4*)(Er + 0);
    const float4 e1 = *(const float4*)(Er + 4);
    const float4 e2 = *(const float4*)(Er + 8);
    const float4 e3 = *(const float4*)(Er + 12);
    double c = (double)e0.x * u4[0].x + (double)e0.y * u4[0].y +
               (double)e0.z * u4[0].z + (double)e0.w * u4[0].w +
               (double)e1.x * u4[1].x + (double)e1.y * u4[1].y +
               (double)e1.z * u4[1].z + (double)e1.w * u4[1].w +
               (double)e2.x * u4[2].x + (double)e2.y * u4[2].y +
               (double)e2.z * u4[2].z + (double)e2.w * u4[2].w +
               (double)e3.x * u4[3].x + (double)e3.y * u4[3].y +
               (double)e3.z * u4[3].z + (double)e3.w * u4[3].w;
    c += __shfl_xor(c, 1);
    c += __shfl_xor(c, 2);
    c += __shfl_xor(c, 4);
    const float v = (float)(1.0 / (131072.0 * c));
    r[0] += (double)(e0.x * v);
    r[1] += (double)(e0.y * v);
    r[2] += (double)(e0.z * v);
    r[3] += (double)(e0.w * v);
    r[4] += (double)(e1.x * v);
    r[5] += (double)(e1.y * v);
    r[6] += (double)(e1.z * v);
    r[7] += (double)(e1.w * v);
    r[8] += (double)(e2.x * v);
    r[9] += (double)(e2.y * v);
    r[10] += (double)(e2.z * v);
    r[11] += (double)(e2.w * v);
    r[12] += (double)(e3.x * v);
    r[13] += (double)(e3.y * v);
    r[14] += (double)(e3.z * v);
    r[15] += (double)(e3.w * v);
  }
  // reduce across the 4 token-slots within each wave (lanes sharing l)
#pragma unroll
  for (int i = 0; i < 16; ++i) {
    r[i] += __shfl_xor(r[i], 8);
    r[i] += __shfl_xor(r[i], 16);
    r[i] += __shfl_xor(r[i], 32);
  }
  if ((tid & 63) < 8) {
    const int w = tid >> 6;
#pragma unroll
    for (int i = 0; i < 16; ++i) part[w][l * 16 + i] = r[i];
  }
  __syncthreads();
  if (tid < KMEM) {
    const double s = part[0][tid] + part[1][tid] + part[2][tid] + part[3][tid];
    RpT[(long)tid * CVBLK + blockIdx.x] = s;
  }
}

// ---------------------------------------------------------------------------
// argmax over k of E[n][k]*u[k]. 8 lanes/token, first-index tiebreak.
// ---------------------------------------------------------------------------
__global__ __launch_bounds__(256) void argmax_kernel(
    const float* __restrict__ E, const float* __restrict__ u,
    int* __restrict__ idx) {
  const int tid = threadIdx.x;
  const int l = tid & 7;
  const int ts = tid >> 3;
  const long n0 = (long)blockIdx.x * 128;
  float4 u4[4];
#pragma unroll
  for (int j = 0; j < 4; ++j) u4[j] = *(const float4*)&u[l * 16 + j * 4];
#pragma unroll
  for (int it = 0; it < 4; ++it) {
    const long n = n0 + it * 32 + ts;
    const float* Er = &E[n * KMEM + l * 16];
    const float4 e0 = *(const float4*)(Er + 0);
    const float4 e1 = *(const float4*)(Er + 4);
    const float4 e2 = *(const float4*)(Er + 8);
    const float4 e3 = *(const float4*)(Er + 12);
    float p[16];
    p[0] = e0.x * u4[0].x; p[1] = e0.y * u4[0].y;
    p[2] = e0.z * u4[0].z; p[3] = e0.w * u4[0].w;
    p[4] = e1.x * u4[1].x; p[5] = e1.y * u4[1].y;
    p[6] = e1.z * u4[1].z; p[7] = e1.w * u4[1].w;
    p[8] = e2.x * u4[2].x; p[9] = e2.y * u4[2].y;
    p[10] = e2.z * u4[2].z; p[11] = e2.w * u4[2].w;
    p[12] = e3.x * u4[3].x; p[13] = e3.y * u4[3].y;
    p[14] = e3.z * u4[3].z; p[15] = e3.w * u4[3].w;
    float bv = p[0];
    int bi = l * 16;
#pragma unroll
    for (int i = 1; i < 16; ++i) {
      if (p[i] > bv) { bv = p[i]; bi = l * 16 + i; }
    }
#pragma unroll
    for (int off = 1; off < 8; off <<= 1) {
      const float ov = __shfl_xor(bv, off);
      const int oi = __shfl_xor(bi, off);
      if (ov > bv || (ov == bv && oi < bi)) { bv = ov; bi = oi; }
    }
    if (l == 0) idx[n] = bi;
  }
}

// ---------------------------------------------------------------------------
// out = (proj + glu_table[idx]) * 0.5, coalesced float4 stream.
// ---------------------------------------------------------------------------
__global__ __launch_bounds__(256) void out_kernel(
    const float* __restrict__ proj, const float* __restrict__ tab,
    const int* __restrict__ idx, float* __restrict__ out) {
  const long base = (long)blockIdx.x * 3072;
#pragma unroll
  for (int j = 0; j < 12; ++j) {
    const long f = base + j * 256 + threadIdx.x;  // float4 index
    const int t = (int)(f / 48);                  // 48 float4 per token row
    const int r = (int)(f - (long)t * 48);
    const int id = idx[t];
    const float4 p = *(const float4*)&proj[f * 4];
    const float4 tb = *(const float4*)&tab[id * DDIM + r * 4];
    float4 o;
    o.x = (p.x + tb.x) * 0.5f;
    o.y = (p.y + tb.y) * 0.5f;
    o.z = (p.z + tb.z) * 0.5f;
    o.w = (p.w + tb.w) * 0.5f;
    *(float4*)&out[f * 4] = o;
  }
}

extern "C" void kernel_launch(void* const* d_in, const int* in_sizes, int n_in,
                              void* d_out, int out_size, void* d_ws,
                              size_t ws_size, hipStream_t stream) {
  const float* proj = (const float*)d_in[0];
  const float* mb = (const float*)d_in[1];
  const float* W = (const float*)d_in[2];
  const float* bias = (const float*)d_in[3];
  float* out = (float*)d_out;
  char* ws = (char*)d_ws;
  // ws layout (~3.87 MB total)
  float* tab = (float*)(ws);                  // 98304 B
  _Float16* bhi = (_Float16*)(ws + 98304);    // 49152 B
  _Float16* blo = (_Float16*)(ws + 147456);   // 49152 B
  float* u1 = (float*)(ws + 196608);          // 512 B
  float* u2 = (float*)(ws + 197120);          // 512 B
  float* u3 = (float*)(ws + 197632);          // 512 B
  int* idx = (int*)(ws + 198144);             // 524288 B
  double* RpA = (double*)(ws + 722432);       // 2 MiB (128 x 2048 fp64)
  double* RpB = (double*)(ws + 2819584);      // 1 MiB (128 x 1024 fp64)
  // E (N x K fp32 = 64 MiB) lives in d_out scratch; consumed before out write.
  float* E = out;

  prep_kernel<<<KMEM, DDIM, 0, stream>>>(mb, W, bias, bhi, blo, tab);
  sim_kernel<<<SIMBLK, 256, 0, stream>>>(proj, bhi, blo, E, RpA);
  u_kernel<<<KMEM, 256, 0, stream>>>(RpA, u1, SIMBLK);
  cv_kernel<<<CVBLK, 256, 0, stream>>>(E, u1, RpB);
  u_kernel<<<KMEM, 256, 0, stream>>>(RpB, u2, CVBLK);
  cv_kernel<<<CVBLK, 256, 0, stream>>>(E, u2, RpB);
  u_kernel<<<KMEM, 256, 0, stream>>>(RpB, u3, CVBLK);
  argmax_kernel<<<CVBLK, 256, 0, stream>>>(E, u3, idx);
  out_kernel<<<2048, 256, 0, stream>>>(proj, tab, idx, out);
}